// Round 18
// baseline (751.428 us; speedup 1.0000x reference)
//
#include <hip/hip_runtime.h>

// InvariantBlock: AFNO spectral block + Galerkin linear attention + GELU FFN
// B=2 H=128 W=128 C=256; tokens 32768; KW=65; HEADS=8 DH=32; NB=16 BS=16 HID=128
// d_in / d_out FP32; intermediates bf16 in ws. Accumulation fp32.
// R17->R18: k_afno_mfma reverted to 64-pos/wave (R16 best) with block = ONE n
// across all 4 waves (grid 16x65): weight fragments L1-shared 4x per block.

typedef unsigned short u16;
typedef unsigned int u32;
typedef __attribute__((ext_vector_type(8))) short bf16x8;
typedef __attribute__((ext_vector_type(8))) unsigned short u16x8;
typedef __attribute__((ext_vector_type(4))) float f32x4;
#define DEV __device__ __forceinline__

constexpr int Cch = 256;
constexpr float EPSN = 1e-5f, LAM = 0.01f;
constexpr float TWO_PI = 6.283185307179586f;

DEV float b2f(u16 u) { return __uint_as_float(((u32)u) << 16); }
DEV u16 f2b(float f) {
  u32 x = __float_as_uint(f);
  return (u16)((x + 0x7FFFu + ((x >> 16) & 1u)) >> 16);
}

// ---------------- init: AFNO weight packs (blocks 0..1023) + twiddles --------
DEV void put2(u16* tw, int m, int idx, float v) {
  u16 hi = f2b(v);
  tw[m * 16384 + idx] = hi;
  tw[(m + 1) * 16384 + idx] = f2b(v - b2f(hi));
}

__global__ __launch_bounds__(256) void k_init(const float* __restrict__ w1,
                                              const float* __restrict__ w2,
                                              u16* __restrict__ W1h, u16* __restrict__ W1l,
                                              u16* __restrict__ W2h, u16* __restrict__ W2l,
                                              u16* __restrict__ tw) {
  int bid = blockIdx.x;
  if (bid < 1024) {
    int idx = bid * 256 + threadIdx.x;
    if (idx < 131072) {
      int n = idx >> 13, rem = idx & 8191;
      int out = rem >> 5, k = rem & 31;
      float v;
      if (out < 128)
        v = (k < 16) ? w1[((size_t)n * 16 + k) * 128 + out]
                     : -w1[((size_t)(16 + n) * 16 + (k - 16)) * 128 + out];
      else {
        int o = out - 128;
        v = (k < 16) ? w1[((size_t)(16 + n) * 16 + k) * 128 + o]
                     : w1[((size_t)n * 16 + (k - 16)) * 128 + o];
      }
      u16 hi = f2b(v);
      W1h[idx] = hi; W1l[idx] = f2b(v - b2f(hi));
    } else if (idx < 262144) {
      int id2 = idx - 131072;
      int n = id2 >> 13, rem = id2 & 8191;
      int out2 = rem >> 8, k = rem & 255;
      float v;
      if (out2 < 16)
        v = (k < 128) ? w2[((size_t)n * 128 + k) * 16 + out2]
                      : -w2[((size_t)(16 + n) * 128 + (k - 128)) * 16 + out2];
      else {
        int o = out2 - 16;
        v = (k < 128) ? w2[((size_t)(16 + n) * 128 + k) * 16 + o]
                      : w2[((size_t)n * 128 + (k - 128)) * 16 + o];
      }
      u16 hi = f2b(v);
      W2h[id2] = hi; W2l[id2] = f2b(v - b2f(hi));
    }
  } else {
    int q = threadIdx.x;
    if (q < 128) {
      int p = bid - 1024;
      int idx = p * 128 + q;
      float ang = TWO_PI * (float)((p * q) & 127) * (1.0f / 128.0f);
      float c = cosf(ang), s = sinf(ang);
      put2(tw, 0, idx, c * (1.0f / 128.0f));
      put2(tw, 2, idx, s * (1.0f / 128.0f));
      put2(tw, 4, idx, -s * (1.0f / 128.0f));
      put2(tw, 6, idx, c);
      put2(tw, 8, idx, s);
      put2(tw, 10, idx, -s);
      u16* wmh = tw + 196608;
      u16* wml = tw + 217088;
      for (int k = q; k < 160; k += 128) {
        float v = 0.0f;
        if (k < 65) {
          float sc = (k == 0 || k == 64) ? 1.0f : 2.0f;
          v = sc * cosf(TWO_PI * (float)((p * k) & 127) * (1.0f / 128.0f)) * (1.0f / 128.0f);
        } else if (k < 130) {
          int kk = k - 65;
          float sc = (kk == 0 || kk == 64) ? 1.0f : 2.0f;
          v = -sc * sinf(TWO_PI * (float)((p * kk) & 127) * (1.0f / 128.0f)) * (1.0f / 128.0f);
        }
        u16 hi = f2b(v);
        wmh[p * 160 + k] = hi;
        wml[p * 160 + k] = f2b(v - b2f(hi));
      }
    }
  }
}

// ---------------- fp32 -> bf16 weight convert --------------------------------
__global__ __launch_bounds__(256) void k_cvt4(const float* __restrict__ s0,
                                              const float* __restrict__ s1,
                                              const float* __restrict__ s2,
                                              const float* __restrict__ s3,
                                              u16* __restrict__ d0, u16* __restrict__ d1,
                                              u16* __restrict__ d2, u16* __restrict__ d3,
                                              int n) {
  int i = blockIdx.x * 256 + threadIdx.x;
  if (i < n) { d0[i] = f2b(s0[i]); d1[i] = f2b(s1[i]); d2[i] = f2b(s2[i]); d3[i] = f2b(s3[i]); }
}

__global__ __launch_bounds__(256) void k_cvt2(const float* __restrict__ s0,
                                              const float* __restrict__ s1,
                                              u16* __restrict__ d0,
                                              u16* __restrict__ d1, int n) {
  int i = blockIdx.x * 256 + threadIdx.x;
  if (i < n) { d0[i] = f2b(s0[i]); d1[i] = f2b(s1[i]); }
}

// ---------------- LayerNorm over C=256; INF=1 fp32 input, else bf16 ----------
template<int INF>
__global__ __launch_bounds__(256) void k_ln(const void* __restrict__ in,
                                            const float* __restrict__ g,
                                            const float* __restrict__ bta,
                                            u16* __restrict__ out) {
  int tid = threadIdx.x, lane = tid & 63;
  size_t token = (size_t)blockIdx.x * 4 + (tid >> 6);
  int c = lane * 4;
  float v[4];
  if (INF) {
    float4 f = *(const float4*)((const float*)in + token * Cch + c);
    v[0] = f.x; v[1] = f.y; v[2] = f.z; v[3] = f.w;
  } else {
    ushort4 u = *(const ushort4*)((const u16*)in + token * Cch + c);
    v[0] = b2f(u.x); v[1] = b2f(u.y); v[2] = b2f(u.z); v[3] = b2f(u.w);
  }
  float s = v[0] + v[1] + v[2] + v[3];
  #pragma unroll
  for (int m = 1; m < 64; m <<= 1) s += __shfl_xor(s, m);
  float mu = s * (1.0f / 256.0f);
  float q = 0.f;
  #pragma unroll
  for (int j = 0; j < 4; j++) { float d = v[j] - mu; q += d * d; }
  #pragma unroll
  for (int m = 1; m < 64; m <<= 1) q += __shfl_xor(q, m);
  float rs = rsqrtf(q * (1.0f / 256.0f) + EPSN);
  ushort4 o;
  o.x = f2b((v[0] - mu) * rs * g[c + 0] + bta[c + 0]);
  o.y = f2b((v[1] - mu) * rs * g[c + 1] + bta[c + 1]);
  o.z = f2b((v[2] - mu) * rs * g[c + 2] + bta[c + 2]);
  o.w = f2b((v[3] - mu) * rs * g[c + 3] + bta[c + 3]);
  *(ushort4*)(out + token * Cch + c) = o;
}

// ------- MFMA forward rDFT over W (cos+sin from one staged tile) -------------
__global__ __launch_bounds__(256) void k_dftw_m(
    const u16* __restrict__ Yg,
    const u16* __restrict__ Chi_, const u16* __restrict__ Clo_,
    const u16* __restrict__ Shi_, const u16* __restrict__ Slo_,
    u16* __restrict__ Or, u16* __restrict__ Oi) {
  __shared__ u16 Bs[128][40];
  int tid = threadIdx.x;
  int bh = blockIdx.x;
  int c0 = blockIdx.y * 128;
  int lane = tid & 63, w = tid >> 6;
  int wm = w >> 1, wn = w & 1;
  int rl = lane & 15, kq = (lane >> 4) * 8, rq = lane >> 4;
  f32x4 accC[4][4] = {};
  f32x4 accS[4][4] = {};
  for (int k0 = 0; k0 < 128; k0 += 32) {
    __syncthreads();
    for (int idx = tid; idx < 1024; idx += 256) {
      int q = idx >> 5, c4 = (idx & 31) * 4;
      ushort4 v = *(const ushort4*)(Yg + ((size_t)bh * 128 + k0 + q) * 256 + c0 + c4);
      Bs[c4 + 0][q] = v.x; Bs[c4 + 1][q] = v.y;
      Bs[c4 + 2][q] = v.z; Bs[c4 + 3][q] = v.w;
    }
    __syncthreads();
    bf16x8 aCh[4], aCl[4], aSh[4], aSl[4], bf[4];
    #pragma unroll
    for (int i = 0; i < 4; i++) {
      int off = (wm * 64 + i * 16 + rl) * 128 + k0 + kq;
      aCh[i] = *(const bf16x8*)(Chi_ + off);
      aCl[i] = *(const bf16x8*)(Clo_ + off);
      aSh[i] = *(const bf16x8*)(Shi_ + off);
      aSl[i] = *(const bf16x8*)(Slo_ + off);
    }
    #pragma unroll
    for (int j = 0; j < 4; j++)
      bf[j] = *(const bf16x8*)&Bs[wn * 64 + j * 16 + rl][kq];
    #pragma unroll
    for (int i = 0; i < 4; i++)
      #pragma unroll
      for (int j = 0; j < 4; j++) {
        accC[i][j] = __builtin_amdgcn_mfma_f32_16x16x32_bf16(aCh[i], bf[j], accC[i][j], 0, 0, 0);
        accC[i][j] = __builtin_amdgcn_mfma_f32_16x16x32_bf16(aCl[i], bf[j], accC[i][j], 0, 0, 0);
        accS[i][j] = __builtin_amdgcn_mfma_f32_16x16x32_bf16(aSh[i], bf[j], accS[i][j], 0, 0, 0);
        accS[i][j] = __builtin_amdgcn_mfma_f32_16x16x32_bf16(aSl[i], bf[j], accS[i][j], 0, 0, 0);
      }
  }
  #pragma unroll
  for (int i = 0; i < 4; i++)
    #pragma unroll
    for (int j = 0; j < 4; j++)
      #pragma unroll
      for (int r = 0; r < 4; r++) {
        int p = wm * 64 + i * 16 + rq * 4 + r;
        if (p < 65) {
          int c = c0 + wn * 64 + j * 16 + rl;
          size_t g = ((size_t)bh * 65 + p) * 256 + c;
          Or[g] = f2b(accC[i][j][r]);
          Oi[g] = f2b(accS[i][j][r]);
        }
      }
}

// ------- MFMA complex DFT over H for fixed (b,kw): O = C*B1 + Ssel*B2 --------
__global__ __launch_bounds__(256) void k_dfth_m(
    const u16* __restrict__ Br_g, const u16* __restrict__ Bi_g,
    const u16* __restrict__ Chi, const u16* __restrict__ Clo,
    const u16* __restrict__ SRhi, const u16* __restrict__ SRlo,
    const u16* __restrict__ SIhi, const u16* __restrict__ SIlo,
    u16* __restrict__ Or, u16* __restrict__ Oi) {
  __shared__ u16 B1s[128][40], B2s[128][40];
  int tid = threadIdx.x;
  int bk = blockIdx.x;
  int b = bk / 65, kw = bk % 65;
  int c0 = (blockIdx.y & 1) * 128;
  int outI = blockIdx.y >> 1;
  const u16* B1g = outI ? Bi_g : Br_g;
  const u16* B2g = outI ? Br_g : Bi_g;
  const u16* Shi = outI ? SIhi : SRhi;
  const u16* Slo = outI ? SIlo : SRlo;
  u16* outp = outI ? Oi : Or;
  int lane = tid & 63, w = tid >> 6;
  int wm = w >> 1, wn = w & 1;
  int rl = lane & 15, kq = (lane >> 4) * 8, rq = lane >> 4;
  f32x4 acc[4][4] = {};
  for (int k0 = 0; k0 < 128; k0 += 32) {
    __syncthreads();
    for (int idx = tid; idx < 1024; idx += 256) {
      int q = idx >> 5, c4 = (idx & 31) * 4;
      size_t g = (((size_t)b * 128 + k0 + q) * 65 + kw) * 256 + c0 + c4;
      ushort4 v1 = *(const ushort4*)(B1g + g);
      ushort4 v2 = *(const ushort4*)(B2g + g);
      B1s[c4 + 0][q] = v1.x; B1s[c4 + 1][q] = v1.y;
      B1s[c4 + 2][q] = v1.z; B1s[c4 + 3][q] = v1.w;
      B2s[c4 + 0][q] = v2.x; B2s[c4 + 1][q] = v2.y;
      B2s[c4 + 2][q] = v2.z; B2s[c4 + 3][q] = v2.w;
    }
    __syncthreads();
    bf16x8 aCh[4], aCl[4], aSh[4], aSl[4], b1[4], b2[4];
    #pragma unroll
    for (int i = 0; i < 4; i++) {
      int off = (wm * 64 + i * 16 + rl) * 128 + k0 + kq;
      aCh[i] = *(const bf16x8*)(Chi + off);
      aCl[i] = *(const bf16x8*)(Clo + off);
      aSh[i] = *(const bf16x8*)(Shi + off);
      aSl[i] = *(const bf16x8*)(Slo + off);
    }
    #pragma unroll
    for (int j = 0; j < 4; j++) {
      b1[j] = *(const bf16x8*)&B1s[wn * 64 + j * 16 + rl][kq];
      b2[j] = *(const bf16x8*)&B2s[wn * 64 + j * 16 + rl][kq];
    }
    #pragma unroll
    for (int i = 0; i < 4; i++)
      #pragma unroll
      for (int j = 0; j < 4; j++) {
        acc[i][j] = __builtin_amdgcn_mfma_f32_16x16x32_bf16(aCh[i], b1[j], acc[i][j], 0, 0, 0);
        acc[i][j] = __builtin_amdgcn_mfma_f32_16x16x32_bf16(aCl[i], b1[j], acc[i][j], 0, 0, 0);
        acc[i][j] = __builtin_amdgcn_mfma_f32_16x16x32_bf16(aSh[i], b2[j], acc[i][j], 0, 0, 0);
        acc[i][j] = __builtin_amdgcn_mfma_f32_16x16x32_bf16(aSl[i], b2[j], acc[i][j], 0, 0, 0);
      }
  }
  #pragma unroll
  for (int i = 0; i < 4; i++)
    #pragma unroll
    for (int j = 0; j < 4; j++)
      #pragma unroll
      for (int r = 0; r < 4; r++) {
        int p = wm * 64 + i * 16 + rq * 4 + r;
        int c = c0 + wn * 64 + j * 16 + rl;
        outp[(((size_t)b * 128 + p) * 65 + kw) * 256 + c] = f2b(acc[i][j][r]);
      }
}

// ------- MFMA inverse rDFT over W + x + ln1out -> X1. K=160 (65r+65i+pad) ----
__global__ __launch_bounds__(256) void k_irfft_m(
    const u16* __restrict__ Ur, const u16* __restrict__ Ui,
    const u16* __restrict__ Whi, const u16* __restrict__ Wlo,
    const float* __restrict__ x_in, const u16* __restrict__ lnout,
    u16* __restrict__ X1) {
  __shared__ u16 Bs[128][40];
  int tid = threadIdx.x;
  int bh = blockIdx.x;
  int c0 = blockIdx.y * 128;
  int lane = tid & 63, w = tid >> 6;
  int wm = w >> 1, wn = w & 1;
  int rl = lane & 15, kq = (lane >> 4) * 8, rq = lane >> 4;
  f32x4 acc[4][4] = {};
  for (int k0 = 0; k0 < 160; k0 += 32) {
    __syncthreads();
    for (int idx = tid; idx < 1024; idx += 256) {
      int q = idx >> 5, c4 = (idx & 31) * 4;
      int grow = k0 + q;
      ushort4 v;
      if (grow < 65)
        v = *(const ushort4*)(Ur + ((size_t)bh * 65 + grow) * 256 + c0 + c4);
      else if (grow < 130)
        v = *(const ushort4*)(Ui + ((size_t)bh * 65 + grow - 65) * 256 + c0 + c4);
      else
        v = make_ushort4(0, 0, 0, 0);
      Bs[c4 + 0][q] = v.x; Bs[c4 + 1][q] = v.y;
      Bs[c4 + 2][q] = v.z; Bs[c4 + 3][q] = v.w;
    }
    __syncthreads();
    bf16x8 ah[4], al[4], bf[4];
    #pragma unroll
    for (int i = 0; i < 4; i++) {
      int off = (wm * 64 + i * 16 + rl) * 160 + k0 + kq;
      ah[i] = *(const bf16x8*)(Whi + off);
      al[i] = *(const bf16x8*)(Wlo + off);
    }
    #pragma unroll
    for (int j = 0; j < 4; j++)
      bf[j] = *(const bf16x8*)&Bs[wn * 64 + j * 16 + rl][kq];
    #pragma unroll
    for (int i = 0; i < 4; i++)
      #pragma unroll
      for (int j = 0; j < 4; j++) {
        acc[i][j] = __builtin_amdgcn_mfma_f32_16x16x32_bf16(ah[i], bf[j], acc[i][j], 0, 0, 0);
        acc[i][j] = __builtin_amdgcn_mfma_f32_16x16x32_bf16(al[i], bf[j], acc[i][j], 0, 0, 0);
      }
  }
  #pragma unroll
  for (int i = 0; i < 4; i++)
    #pragma unroll
    for (int j = 0; j < 4; j++)
      #pragma unroll
      for (int r = 0; r < 4; r++) {
        int p = wm * 64 + i * 16 + rq * 4 + r;
        int c = c0 + wn * 64 + j * 16 + rl;
        size_t g = ((size_t)bh * 128 + p) * 256 + c;
        X1[g] = f2b(x_in[g] + b2f(lnout[g]) + acc[i][j][r]);
      }
}

// ------- fused AFNO MLP, barrier-free, 64 pos/wave, block = ONE n ------------
// All 4 waves share the same n -> weight fragment loads hit L1 4x.
__global__ __launch_bounds__(256) void k_afno_mfma(
    const u16* __restrict__ Zr, const u16* __restrict__ Zi,
    const u16* __restrict__ W1h, const u16* __restrict__ W1l,
    const u16* __restrict__ W2h, const u16* __restrict__ W2l,
    const float* __restrict__ b1, const float* __restrict__ b2,
    u16* __restrict__ Or, u16* __restrict__ Oi) {
  __shared__ u16 o1buf[4][64][74];
  int tid = threadIdx.x;
  int lane = tid & 63, w = tid >> 6;
  int n = blockIdx.x;
  int p0 = (blockIdx.y * 4 + w) * 64;
  int rl = lane & 15, rq = lane >> 4, kq = rq * 8;
  bf16x8 bfr[4];
  #pragma unroll
  for (int j = 0; j < 4; j++) {
    int p = p0 + j * 16 + rl;
    const u16* src = (kq < 16) ? (Zr + (size_t)p * 256 + n * 16 + kq)
                               : (Zi + (size_t)p * 256 + n * 16 + kq - 16);
    bfr[j] = *(const bf16x8*)src;
  }
  f32x4 acc2[2][4] = {};
  for (int c = 0; c < 4; c++) {
    f32x4 a1[4][4] = {};
    #pragma unroll
    for (int i = 0; i < 4; i++) {
      int out = c * 64 + i * 16 + rl;
      bf16x8 ah = *(const bf16x8*)(W1h + ((size_t)n * 256 + out) * 32 + kq);
      bf16x8 al = *(const bf16x8*)(W1l + ((size_t)n * 256 + out) * 32 + kq);
      #pragma unroll
      for (int j = 0; j < 4; j++) {
        a1[i][j] = __builtin_amdgcn_mfma_f32_16x16x32_bf16(ah, bfr[j], a1[i][j], 0, 0, 0);
        a1[i][j] = __builtin_amdgcn_mfma_f32_16x16x32_bf16(al, bfr[j], a1[i][j], 0, 0, 0);
      }
    }
    #pragma unroll
    for (int i = 0; i < 4; i++) {
      float bv[4];
      #pragma unroll
      for (int r = 0; r < 4; r++) {
        int out = c * 64 + i * 16 + rq * 4 + r;
        bv[r] = (out < 128) ? b1[n * 128 + out] : b1[2048 + n * 128 + out - 128];
      }
      #pragma unroll
      for (int j = 0; j < 4; j++) {
        int pos = j * 16 + rl;
        ushort4 pk;
        u16* pp = &pk.x;
        #pragma unroll
        for (int r = 0; r < 4; r++)
          pp[r] = f2b(fmaxf(a1[i][j][r] + bv[r], 0.0f));
        *(ushort4*)&o1buf[w][pos][(i * 16 + rq * 4) ^ ((pos & 7) << 3)] = pk;
      }
    }
    #pragma unroll
    for (int ks = 0; ks < 2; ks++) {
      int kg = c * 64 + ks * 32 + kq;
      #pragma unroll
      for (int i2 = 0; i2 < 2; i2++) {
        int out2 = i2 * 16 + rl;
        bf16x8 ah = *(const bf16x8*)(W2h + ((size_t)n * 32 + out2) * 256 + kg);
        bf16x8 al = *(const bf16x8*)(W2l + ((size_t)n * 32 + out2) * 256 + kg);
        #pragma unroll
        for (int j = 0; j < 4; j++) {
          int pos = j * 16 + rl;
          bf16x8 bb = *(const bf16x8*)&o1buf[w][pos][(ks * 32 + kq) ^ ((pos & 7) << 3)];
          acc2[i2][j] = __builtin_amdgcn_mfma_f32_16x16x32_bf16(ah, bb, acc2[i2][j], 0, 0, 0);
          acc2[i2][j] = __builtin_amdgcn_mfma_f32_16x16x32_bf16(al, bb, acc2[i2][j], 0, 0, 0);
        }
      }
    }
  }
  #pragma unroll
  for (int i2 = 0; i2 < 2; i2++)
    #pragma unroll
    for (int r = 0; r < 4; r++) {
      int out2 = i2 * 16 + rq * 4 + r;
      float bv = (out2 < 16) ? b2[n * 16 + out2] : b2[256 + n * 16 + out2 - 16];
      int ch = (out2 < 16) ? out2 : out2 - 16;
      #pragma unroll
      for (int j = 0; j < 4; j++) {
        float v = acc2[i2][j][r] + bv;
        v = copysignf(fmaxf(fabsf(v) - LAM, 0.0f), v);
        size_t g = (size_t)(p0 + j * 16 + rl) * 256 + n * 16 + ch;
        if (out2 < 16) Or[g] = f2b(v);
        else Oi[g] = f2b(v);
      }
    }
}

// ------- MFMA GEMM 128x128: C[m,n] = act(A*B^T + bias) (+resid) --------------
template<int ACT, int RT, int OUTF>
__global__ __launch_bounds__(256) void k_mgemm(const u16* __restrict__ Ap,
                                               const u16* __restrict__ Bp,
                                               const float* __restrict__ bias,
                                               const u16* __restrict__ resid,
                                               void* __restrict__ Cp,
                                               int M, int N, int K) {
  __shared__ u16 As[128][40];
  __shared__ u16 Bs[128][40];
  int tid = threadIdx.x;
  int lane = tid & 63, w = tid >> 6;
  int wm = w >> 1, wn = w & 1;
  int m0 = blockIdx.x * 128, n0 = blockIdx.y * 128;
  int srow = tid >> 1, sseg = tid & 1;
  const u16* ag = Ap + (size_t)(m0 + srow) * K + sseg * 16;
  const u16* bg = Bp + (size_t)(n0 + srow) * K + sseg * 16;
  int rl = lane & 15, kq = (lane >> 4) * 8;
  f32x4 acc[4][4] = {};
  for (int k0 = 0; k0 < K; k0 += 32) {
    __syncthreads();
    *(u16x8*)&As[srow][sseg * 16]     = *(const u16x8*)(ag + k0);
    *(u16x8*)&As[srow][sseg * 16 + 8] = *(const u16x8*)(ag + k0 + 8);
    *(u16x8*)&Bs[srow][sseg * 16]     = *(const u16x8*)(bg + k0);
    *(u16x8*)&Bs[srow][sseg * 16 + 8] = *(const u16x8*)(bg + k0 + 8);
    __syncthreads();
    bf16x8 af[4], bf[4];
    #pragma unroll
    for (int i = 0; i < 4; i++) {
      af[i] = *(const bf16x8*)&As[wm * 64 + i * 16 + rl][kq];
      bf[i] = *(const bf16x8*)&Bs[wn * 64 + i * 16 + rl][kq];
    }
    #pragma unroll
    for (int i = 0; i < 4; i++)
      #pragma unroll
      for (int j = 0; j < 4; j++)
        acc[i][j] = __builtin_amdgcn_mfma_f32_16x16x32_bf16(af[i], bf[j], acc[i][j], 0, 0, 0);
  }
  int rq = lane >> 4;
  #pragma unroll
  for (int i = 0; i < 4; i++) {
    #pragma unroll
    for (int j = 0; j < 4; j++) {
      #pragma unroll
      for (int r = 0; r < 4; r++) {
        int m = m0 + wm * 64 + i * 16 + rq * 4 + r;
        int n = n0 + wn * 64 + j * 16 + rl;
        float v = acc[i][j][r] + bias[n];
        if (ACT) v = 0.5f * v * (1.0f + erff(v * 0.70710678118654752f));
        if (RT) v += b2f(resid[(size_t)m * N + n]);
        if (OUTF) ((float*)Cp)[(size_t)m * N + n] = v;
        else ((u16*)Cp)[(size_t)m * N + n] = f2b(v);
      }
    }
  }
}

// ------- fused QKV GEMM + per-head LN on K,V: grid (256, 6) ------------------
__global__ __launch_bounds__(256) void k_mgemm_qkv(
    const u16* __restrict__ Ap,
    const u16* __restrict__ Wk, const u16* __restrict__ Wv, const u16* __restrict__ Wq,
    const float* __restrict__ bk, const float* __restrict__ bv, const float* __restrict__ bq,
    const float* __restrict__ lnkg, const float* __restrict__ lnkb,
    const float* __restrict__ lnvg, const float* __restrict__ lnvb,
    u16* __restrict__ Ko, u16* __restrict__ Vo, u16* __restrict__ Qo) {
  __shared__ u16 As[128][40];
  __shared__ u16 Bs[128][40];
  int sel = blockIdx.y >> 1;
  const u16* Bp = (sel == 0) ? Wk : (sel == 1) ? Wv : Wq;
  const float* bias = (sel == 0) ? bk : (sel == 1) ? bv : bq;
  u16* Cp = (sel == 0) ? Ko : (sel == 1) ? Vo : Qo;
  int tid = threadIdx.x;
  int lane = tid & 63, w = tid >> 6;
  int wm = w >> 1, wn = w & 1;
  int m0 = blockIdx.x * 128, n0 = (blockIdx.y & 1) * 128;
  int srow = tid >> 1, sseg = tid & 1;
  const u16* ag = Ap + (size_t)(m0 + srow) * 256 + sseg * 16;
  const u16* bg = Bp + (size_t)(n0 + srow) * 256 + sseg * 16;
  int rl = lane & 15, kq = (lane >> 4) * 8;
  f32x4 acc[4][4] = {};
  for (int k0 = 0; k0 < 256; k0 += 32) {
    __syncthreads();
    *(u16x8*)&As[srow][sseg * 16]     = *(const u16x8*)(ag + k0);
    *(u16x8*)&As[srow][sseg * 16 + 8] = *(const u16x8*)(ag + k0 + 8);
    *(u16x8*)&Bs[srow][sseg * 16]     = *(const u16x8*)(bg + k0);
    *(u16x8*)&Bs[srow][sseg * 16 + 8] = *(const u16x8*)(bg + k0 + 8);
    __syncthreads();
    bf16x8 af[4], bf[4];
    #pragma unroll
    for (int i = 0; i < 4; i++) {
      af[i] = *(const bf16x8*)&As[wm * 64 + i * 16 + rl][kq];
      bf[i] = *(const bf16x8*)&Bs[wn * 64 + i * 16 + rl][kq];
    }
    #pragma unroll
    for (int i = 0; i < 4; i++)
      #pragma unroll
      for (int j = 0; j < 4; j++)
        acc[i][j] = __builtin_amdgcn_mfma_f32_16x16x32_bf16(af[i], bf[j], acc[i][j], 0, 0, 0);
  }
  int rq = lane >> 4;
  if (sel == 2) {
    #pragma unroll
    for (int i = 0; i < 4; i++)
      #pragma unroll
      for (int j = 0; j < 4; j++)
        #pragma unroll
        for (int r = 0; r < 4; r++) {
          int m = m0 + wm * 64 + i * 16 + rq * 4 + r;
          int n = n0 + wn * 64 + j * 16 + rl;
          Cp[(size_t)m * 256 + n] = f2b(acc[i][j][r] + bias[n]);
        }
  } else {
    const float* g = sel ? lnvg : lnkg;
    const float* bt = sel ? lnvb : lnkb;
    #pragma unroll
    for (int i = 0; i < 4; i++)
      #pragma unroll
      for (int r = 0; r < 4; r++) {
        int m = m0 + wm * 64 + i * 16 + rq * 4 + r;
        #pragma unroll
        for (int hb = 0; hb < 2; hb++) {
          int hbase = n0 + wn * 64 + hb * 32;
          float v0 = acc[i][hb * 2 + 0][r] + bias[hbase + rl];
          float v1 = acc[i][hb * 2 + 1][r] + bias[hbase + 16 + rl];
          float s = v0 + v1;
          s += __shfl_xor(s, 1); s += __shfl_xor(s, 2);
          s += __shfl_xor(s, 4); s += __shfl_xor(s, 8);
          float mu = s * (1.0f / 32.0f);
          float q = (v0 - mu) * (v0 - mu) + (v1 - mu) * (v1 - mu);
          q += __shfl_xor(q, 1); q += __shfl_xor(q, 2);
          q += __shfl_xor(q, 4); q += __shfl_xor(q, 8);
          float rs = rsqrtf(q * (1.0f / 32.0f) + EPSN);
          float o0 = (v0 - mu) * rs * g[hbase + rl] + bt[hbase + rl];
          float o1 = (v1 - mu) * rs * g[hbase + 16 + rl] + bt[hbase + 16 + rl];
          Cp[(size_t)m * 256 + hbase + rl] = f2b(o0);
          Cp[(size_t)m * 256 + hbase + 16 + rl] = f2b(o1);
        }
      }
  }
}

// ------- MFMA GEMM 64x64 tile (FFN down: K=2048, grid (64,4)) ----------------
__global__ __launch_bounds__(256) void k_mgemm_d(const u16* __restrict__ Ap,
                                                 const u16* __restrict__ Bp,
                                                 const float* __restrict__ bias,
                                                 const u16* __restrict__ resid,
                                                 float* __restrict__ Cp,
                                                 int M, int N, int K) {
  __shared__ u16 As[64][40];
  __shared__ u16 Bs[64][40];
  int tid = threadIdx.x;
  int lane = tid & 63, w = tid >> 6;
  int wm = w >> 1, wn = w & 1;
  int m0 = blockIdx.x * 64, n0 = blockIdx.y * 64;
  int srow = tid >> 2, sseg = tid & 3;
  const u16* ag = Ap + (size_t)(m0 + srow) * K + sseg * 8;
  const u16* bg = Bp + (size_t)(n0 + srow) * K + sseg * 8;
  int rl = lane & 15, kq = (lane >> 4) * 8;
  f32x4 acc[2][2] = {};
  for (int k0 = 0; k0 < K; k0 += 32) {
    __syncthreads();
    *(u16x8*)&As[srow][sseg * 8] = *(const u16x8*)(ag + k0);
    *(u16x8*)&Bs[srow][sseg * 8] = *(const u16x8*)(bg + k0);
    __syncthreads();
    bf16x8 af[2], bf[2];
    #pragma unroll
    for (int i = 0; i < 2; i++) {
      af[i] = *(const bf16x8*)&As[wm * 32 + i * 16 + rl][kq];
      bf[i] = *(const bf16x8*)&Bs[wn * 32 + i * 16 + rl][kq];
    }
    #pragma unroll
    for (int i = 0; i < 2; i++)
      #pragma unroll
      for (int j = 0; j < 2; j++)
        acc[i][j] = __builtin_amdgcn_mfma_f32_16x16x32_bf16(af[i], bf[j], acc[i][j], 0, 0, 0);
  }
  int rq = lane >> 4;
  #pragma unroll
  for (int i = 0; i < 2; i++)
    #pragma unroll
    for (int j = 0; j < 2; j++)
      #pragma unroll
      for (int r = 0; r < 4; r++) {
        int m = m0 + wm * 32 + i * 16 + rq * 4 + r;
        int n = n0 + wn * 32 + j * 16 + rl;
        float v = acc[i][j][r] + bias[n] + b2f(resid[(size_t)m * N + n]);
        Cp[(size_t)m * N + n] = v;
      }
}

// ---------------- kv partial sums over 16 chunks of 1024 tokens --------------
__global__ __launch_bounds__(256) void k_kv_partial(const u16* __restrict__ Kb,
                                                    const u16* __restrict__ Vb,
                                                    float* __restrict__ part) {
  __shared__ float kl[64][33], vl[64][33];
  int tid = threadIdx.x;
  int bh = blockIdx.x;
  int b = bh >> 3, h = bh & 7;
  int n0 = blockIdx.y * 1024;
  int d = tid >> 3, eg = tid & 7;
  float acc[4] = {0.f, 0.f, 0.f, 0.f};
  for (int sub = 0; sub < 16; sub++) {
    __syncthreads();
    for (int idx = tid; idx < 64 * 32; idx += 256) {
      int nn = idx >> 5, c = idx & 31;
      size_t o = ((size_t)(b * 16384 + n0 + sub * 64 + nn)) * Cch + h * 32 + c;
      kl[nn][c] = b2f(Kb[o]); vl[nn][c] = b2f(Vb[o]);
    }
    __syncthreads();
    #pragma unroll 4
    for (int nn = 0; nn < 64; nn++) {
      float kd = kl[nn][d];
      #pragma unroll
      for (int j = 0; j < 4; j++) acc[j] += kd * vl[nn][eg * 4 + j];
    }
  }
  size_t base = ((size_t)bh * 16 + blockIdx.y) * 1024 + d * 32 + eg * 4;
  #pragma unroll
  for (int j = 0; j < 4; j++) part[base + j] = acc[j];
}

// reduce partials -> kvT (transposed [e][d]) hi/lo bf16, fp32-accurate pair
__global__ __launch_bounds__(1024) void k_kv_reduce(const float* __restrict__ part,
                                                    u16* __restrict__ kvTh,
                                                    u16* __restrict__ kvTl) {
  int bh = blockIdx.x, o = threadIdx.x;
  float s = 0.f;
  #pragma unroll
  for (int p = 0; p < 16; p++) s += part[((size_t)bh * 16 + p) * 1024 + o];
  s *= (1.0f / 16384.0f);
  int d = o >> 5, e = o & 31;
  u16 hi = f2b(s);
  kvTh[(size_t)bh * 1024 + e * 32 + d] = hi;
  kvTl[(size_t)bh * 1024 + e * 32 + d] = f2b(s - b2f(hi));
}

// ------- MFMA attn: ATT[t, h*32+e] = sum_d Q[t, h*32+d] * kvT[b,h][e][d] ----
__global__ __launch_bounds__(256) void k_attn_m(const u16* __restrict__ Q,
                                                const u16* __restrict__ kvTh,
                                                const u16* __restrict__ kvTl,
                                                u16* __restrict__ ATT) {
  int tid = threadIdx.x;
  int lane = tid & 63, w = tid >> 6;
  int h = blockIdx.y;
  int t0 = blockIdx.x * 64 + w * 16;
  int b = t0 >> 14;
  int rl = lane & 15, rq = lane >> 4, kq = rq * 8;
  bf16x8 a = *(const bf16x8*)(Q + (size_t)(t0 + rl) * 256 + h * 32 + kq);
  const u16* kh = kvTh + (size_t)(b * 8 + h) * 1024;
  const u16* kl = kvTl + (size_t)(b * 8 + h) * 1024;
  f32x4 acc[2] = {};
  #pragma unroll
  for (int j = 0; j < 2; j++) {
    bf16x8 bh_ = *(const bf16x8*)(kh + (j * 16 + rl) * 32 + kq);
    bf16x8 bl_ = *(const bf16x8*)(kl + (j * 16 + rl) * 32 + kq);
    acc[j] = __builtin_amdgcn_mfma_f32_16x16x32_bf16(a, bh_, acc[j], 0, 0, 0);
    acc[j] = __builtin_amdgcn_mfma_f32_16x16x32_bf16(a, bl_, acc[j], 0, 0, 0);
  }
  #pragma unroll
  for (int j = 0; j < 2; j++)
    #pragma unroll
    for (int r = 0; r < 4; r++)
      ATT[(size_t)(t0 + rq * 4 + r) * 256 + h * 32 + j * 16 + rl] = f2b(acc[j][r]);
}

extern "C" void kernel_launch(void* const* d_in, const int* in_sizes, int n_in,
                              void* d_out, int out_size, void* d_ws, size_t ws_size,
                              hipStream_t stream) {
  (void)in_sizes; (void)n_in; (void)out_size; (void)ws_size;
  const float* x    = (const float*)d_in[0];
  const float* w1   = (const float*)d_in[1];
  const float* b1   = (const float*)d_in[2];
  const float* w2   = (const float*)d_in[3];
  const float* b2   = (const float*)d_in[4];
  const float* wq   = (const float*)d_in[5];
  const float* bq   = (const float*)d_in[6];
  const float* wk   = (const float*)d_in[7];
  const float* bk   = (const float*)d_in[8];
  const float* wv   = (const float*)d_in[9];
  const float* bv   = (const float*)d_in[10];
  const float* lnkg = (const float*)d_in[11];
  const float* lnkb = (const float*)d_in[12];
  const float* lnvg = (const float*)d_in[13];
  const float* lnvb = (const float*)d_in[14];
  const float* wo   = (const float*)d_in[15];
  const float* bo   = (const float*)d_in[16];
  const float* wup  = (const float*)d_in[17];
  const float* bup  = (const float*)d_in[18];
  const float* wdn  = (const float*)d_in[19];
  const float* bdn  = (const float*)d_in[20];
  const float* n1g  = (const float*)d_in[21];
  const float* n1b  = (const float*)d_in[22];
  const float* n2g  = (const float*)d_in[23];
  const float* n2b  = (const float*)d_in[24];
  const float* n3g  = (const float*)d_in[25];
  const float* n3b  = (const float*)d_in[26];

  // ws layout (max 51,970,048, proven safe). Qb in d_out scratch.
  char* ws = (char*)d_ws;
  u16* A    = (u16*)(ws + 0);
  u16* S1r  = (u16*)(ws + 16777216);
  u16* S1i  = (u16*)(ws + 25296896);
  u16* S2r  = (u16*)(ws + 33816576);
  u16* S2i  = (u16*)(ws + 42336256);
  u16* X1   = (u16*)(ws + 16777216);
  u16* Vb   = (u16*)(ws + 16777216);
  u16* X2   = (u16*)(ws + 16777216);
  u16* Kb   = (u16*)(ws + 33816576);
  u16* ATT  = (u16*)(ws + 33816576);
  u16* UP   = (u16*)(ws + 33816576);
  u16* wq_b = (u16*)(ws + 33554432);
  u16* wk_b = (u16*)(ws + 33685504);
  u16* wv_b = (u16*)(ws + 50593792);
  u16* wo_b = (u16*)(ws + 50724864);
  u16* wup_b = (u16*)(ws + 16777216);
  u16* wdn_b = (u16*)(ws + 17825792);
  u16* TW   = (u16*)(ws + 50855936);
  float* KVp = (float*)(ws + 50855936);
  u16* kvTh = (u16*)(ws + 51904512);
  u16* kvTl = (u16*)(ws + 51937280);
  float* outp = (float*)d_out;
  u16* Qb  = (u16*)d_out;
  u16* W1h = (u16*)d_out;
  u16* W1l = W1h + 131072;
  u16* W2h = W1h + 262144;
  u16* W2l = W1h + 393216;

  u16 *Cf_h = TW + 0 * 16384, *Cf_l = TW + 1 * 16384;
  u16 *Sf_h = TW + 2 * 16384, *Sf_l = TW + 3 * 16384;
  u16 *Snf_h = TW + 4 * 16384, *Snf_l = TW + 5 * 16384;
  u16 *Cu_h = TW + 6 * 16384, *Cu_l = TW + 7 * 16384;
  u16 *Su_h = TW + 8 * 16384, *Su_l = TW + 9 * 16384;
  u16 *Snu_h = TW + 10 * 16384, *Snu_l = TW + 11 * 16384;
  u16 *Wm_h = TW + 196608, *Wm_l = TW + 217088;

  k_init<<<1152, 256, 0, stream>>>(w1, w2, W1h, W1l, W2h, W2l, TW);

  // ---- AFNO: x1 = x + ln1(x) + irfft2(shrink(mlp(rfft2(ln1(x))))) ----
  k_ln<1><<<8192, 256, 0, stream>>>((const void*)x, n1g, n1b, A);
  k_dftw_m<<<dim3(256, 2), 256, 0, stream>>>(A, Cu_h, Cu_l, Snu_h, Snu_l, S1r, S1i);
  k_dfth_m<<<dim3(130, 4), 256, 0, stream>>>(S1r, S1i, Cf_h, Cf_l, Sf_h, Sf_l, Snf_h, Snf_l, S2r, S2i);
  k_afno_mfma<<<dim3(16, 65), 256, 0, stream>>>(S2r, S2i, W1h, W1l, W2h, W2l, b1, b2, S1r, S1i);
  k_dfth_m<<<dim3(130, 4), 256, 0, stream>>>(S1r, S1i, Cu_h, Cu_l, Snu_h, Snu_l, Su_h, Su_l, S2r, S2i);
  k_irfft_m<<<dim3(256, 2), 256, 0, stream>>>(S2r, S2i, Wm_h, Wm_l, x, A, X1);

  // ---- convert QKV/O weights to bf16 (dead S1i/S2i slack) ----
  k_cvt4<<<256, 256, 0, stream>>>(wq, wk, wv, wo, wq_b, wk_b, wv_b, wo_b, 65536);

  // ---- Galerkin: x2 = ln2(x1) + wo(attn) ; residual = LN2 OUTPUT ----
  k_ln<0><<<8192, 256, 0, stream>>>((const void*)X1, n2g, n2b, A);
  k_mgemm_qkv<<<dim3(256, 6), 256, 0, stream>>>(A, wk_b, wv_b, wq_b, bk, bv, bq,
                                                lnkg, lnkb, lnvg, lnvb, Kb, Vb, Qb);
  k_kv_partial<<<dim3(16, 16), 256, 0, stream>>>(Kb, Vb, KVp);
  k_kv_reduce<<<16, 1024, 0, stream>>>(KVp, kvTh, kvTl);
  k_attn_m<<<dim3(512, 8), 256, 0, stream>>>(Qb, kvTh, kvTl, ATT);
  k_mgemm<0, 1, 0><<<dim3(256, 2), 256, 0, stream>>>(ATT, wo_b, bo, A, (void*)X2, 32768, 256, 256);

  // ---- FFN: out = ln3(x2) + down(gelu(up(ln3))) ; residual = LN3 OUTPUT ----
  k_ln<0><<<8192, 256, 0, stream>>>((const void*)X2, n3g, n3b, A);
  k_cvt2<<<2048, 256, 0, stream>>>(wup, wdn, wup_b, wdn_b, 524288);
  for (int c = 0; c < 8; c++) {
    const u16* Ac = A + (size_t)c * 4096 * 256;
    k_mgemm<1, 0, 0><<<dim3(32, 16), 256, 0, stream>>>(Ac, wup_b, bup, nullptr, (void*)UP, 4096, 2048, 256);
    k_mgemm_d<<<dim3(64, 4), 256, 0, stream>>>(UP, wdn_b, bdn, Ac, outp + (size_t)c * 4096 * 256, 4096, 256, 2048);
  }
}

// Round 19
// 736.697 us; speedup vs baseline: 1.0200x; 1.0200x over previous
//
#include <hip/hip_runtime.h>

// InvariantBlock: AFNO spectral block + Galerkin linear attention + GELU FFN
// B=2 H=128 W=128 C=256; tokens 32768; KW=65; HEADS=8 DH=32; NB=16 BS=16 HID=128
// d_in / d_out FP32; intermediates bf16 in ws. Accumulation fp32.
// R18->R19: k_afno_mfma restored to R16's measured-best config (grid 4x260,
// 4 n/block, 64 pos/wave). Both R17 (pos-split) and R18 (n-share) regressed;
// R16 is the local optimum (FETCH 9.4MB, 58us).

typedef unsigned short u16;
typedef unsigned int u32;
typedef __attribute__((ext_vector_type(8))) short bf16x8;
typedef __attribute__((ext_vector_type(8))) unsigned short u16x8;
typedef __attribute__((ext_vector_type(4))) float f32x4;
#define DEV __device__ __forceinline__

constexpr int Cch = 256;
constexpr float EPSN = 1e-5f, LAM = 0.01f;
constexpr float TWO_PI = 6.283185307179586f;

DEV float b2f(u16 u) { return __uint_as_float(((u32)u) << 16); }
DEV u16 f2b(float f) {
  u32 x = __float_as_uint(f);
  return (u16)((x + 0x7FFFu + ((x >> 16) & 1u)) >> 16);
}

// ---------------- init: AFNO weight packs (blocks 0..1023) + twiddles --------
DEV void put2(u16* tw, int m, int idx, float v) {
  u16 hi = f2b(v);
  tw[m * 16384 + idx] = hi;
  tw[(m + 1) * 16384 + idx] = f2b(v - b2f(hi));
}

__global__ __launch_bounds__(256) void k_init(const float* __restrict__ w1,
                                              const float* __restrict__ w2,
                                              u16* __restrict__ W1h, u16* __restrict__ W1l,
                                              u16* __restrict__ W2h, u16* __restrict__ W2l,
                                              u16* __restrict__ tw) {
  int bid = blockIdx.x;
  if (bid < 1024) {
    int idx = bid * 256 + threadIdx.x;
    if (idx < 131072) {
      int n = idx >> 13, rem = idx & 8191;
      int out = rem >> 5, k = rem & 31;
      float v;
      if (out < 128)
        v = (k < 16) ? w1[((size_t)n * 16 + k) * 128 + out]
                     : -w1[((size_t)(16 + n) * 16 + (k - 16)) * 128 + out];
      else {
        int o = out - 128;
        v = (k < 16) ? w1[((size_t)(16 + n) * 16 + k) * 128 + o]
                     : w1[((size_t)n * 16 + (k - 16)) * 128 + o];
      }
      u16 hi = f2b(v);
      W1h[idx] = hi; W1l[idx] = f2b(v - b2f(hi));
    } else if (idx < 262144) {
      int id2 = idx - 131072;
      int n = id2 >> 13, rem = id2 & 8191;
      int out2 = rem >> 8, k = rem & 255;
      float v;
      if (out2 < 16)
        v = (k < 128) ? w2[((size_t)n * 128 + k) * 16 + out2]
                      : -w2[((size_t)(16 + n) * 128 + (k - 128)) * 16 + out2];
      else {
        int o = out2 - 16;
        v = (k < 128) ? w2[((size_t)(16 + n) * 128 + k) * 16 + o]
                      : w2[((size_t)n * 128 + (k - 128)) * 16 + o];
      }
      u16 hi = f2b(v);
      W2h[id2] = hi; W2l[id2] = f2b(v - b2f(hi));
    }
  } else {
    int q = threadIdx.x;
    if (q < 128) {
      int p = bid - 1024;
      int idx = p * 128 + q;
      float ang = TWO_PI * (float)((p * q) & 127) * (1.0f / 128.0f);
      float c = cosf(ang), s = sinf(ang);
      put2(tw, 0, idx, c * (1.0f / 128.0f));
      put2(tw, 2, idx, s * (1.0f / 128.0f));
      put2(tw, 4, idx, -s * (1.0f / 128.0f));
      put2(tw, 6, idx, c);
      put2(tw, 8, idx, s);
      put2(tw, 10, idx, -s);
      u16* wmh = tw + 196608;
      u16* wml = tw + 217088;
      for (int k = q; k < 160; k += 128) {
        float v = 0.0f;
        if (k < 65) {
          float sc = (k == 0 || k == 64) ? 1.0f : 2.0f;
          v = sc * cosf(TWO_PI * (float)((p * k) & 127) * (1.0f / 128.0f)) * (1.0f / 128.0f);
        } else if (k < 130) {
          int kk = k - 65;
          float sc = (kk == 0 || kk == 64) ? 1.0f : 2.0f;
          v = -sc * sinf(TWO_PI * (float)((p * kk) & 127) * (1.0f / 128.0f)) * (1.0f / 128.0f);
        }
        u16 hi = f2b(v);
        wmh[p * 160 + k] = hi;
        wml[p * 160 + k] = f2b(v - b2f(hi));
      }
    }
  }
}

// ---------------- fp32 -> bf16 weight convert --------------------------------
__global__ __launch_bounds__(256) void k_cvt4(const float* __restrict__ s0,
                                              const float* __restrict__ s1,
                                              const float* __restrict__ s2,
                                              const float* __restrict__ s3,
                                              u16* __restrict__ d0, u16* __restrict__ d1,
                                              u16* __restrict__ d2, u16* __restrict__ d3,
                                              int n) {
  int i = blockIdx.x * 256 + threadIdx.x;
  if (i < n) { d0[i] = f2b(s0[i]); d1[i] = f2b(s1[i]); d2[i] = f2b(s2[i]); d3[i] = f2b(s3[i]); }
}

__global__ __launch_bounds__(256) void k_cvt2(const float* __restrict__ s0,
                                              const float* __restrict__ s1,
                                              u16* __restrict__ d0,
                                              u16* __restrict__ d1, int n) {
  int i = blockIdx.x * 256 + threadIdx.x;
  if (i < n) { d0[i] = f2b(s0[i]); d1[i] = f2b(s1[i]); }
}

// ---------------- LayerNorm over C=256; INF=1 fp32 input, else bf16 ----------
template<int INF>
__global__ __launch_bounds__(256) void k_ln(const void* __restrict__ in,
                                            const float* __restrict__ g,
                                            const float* __restrict__ bta,
                                            u16* __restrict__ out) {
  int tid = threadIdx.x, lane = tid & 63;
  size_t token = (size_t)blockIdx.x * 4 + (tid >> 6);
  int c = lane * 4;
  float v[4];
  if (INF) {
    float4 f = *(const float4*)((const float*)in + token * Cch + c);
    v[0] = f.x; v[1] = f.y; v[2] = f.z; v[3] = f.w;
  } else {
    ushort4 u = *(const ushort4*)((const u16*)in + token * Cch + c);
    v[0] = b2f(u.x); v[1] = b2f(u.y); v[2] = b2f(u.z); v[3] = b2f(u.w);
  }
  float s = v[0] + v[1] + v[2] + v[3];
  #pragma unroll
  for (int m = 1; m < 64; m <<= 1) s += __shfl_xor(s, m);
  float mu = s * (1.0f / 256.0f);
  float q = 0.f;
  #pragma unroll
  for (int j = 0; j < 4; j++) { float d = v[j] - mu; q += d * d; }
  #pragma unroll
  for (int m = 1; m < 64; m <<= 1) q += __shfl_xor(q, m);
  float rs = rsqrtf(q * (1.0f / 256.0f) + EPSN);
  ushort4 o;
  o.x = f2b((v[0] - mu) * rs * g[c + 0] + bta[c + 0]);
  o.y = f2b((v[1] - mu) * rs * g[c + 1] + bta[c + 1]);
  o.z = f2b((v[2] - mu) * rs * g[c + 2] + bta[c + 2]);
  o.w = f2b((v[3] - mu) * rs * g[c + 3] + bta[c + 3]);
  *(ushort4*)(out + token * Cch + c) = o;
}

// ------- MFMA forward rDFT over W (cos+sin from one staged tile) -------------
__global__ __launch_bounds__(256) void k_dftw_m(
    const u16* __restrict__ Yg,
    const u16* __restrict__ Chi_, const u16* __restrict__ Clo_,
    const u16* __restrict__ Shi_, const u16* __restrict__ Slo_,
    u16* __restrict__ Or, u16* __restrict__ Oi) {
  __shared__ u16 Bs[128][40];
  int tid = threadIdx.x;
  int bh = blockIdx.x;
  int c0 = blockIdx.y * 128;
  int lane = tid & 63, w = tid >> 6;
  int wm = w >> 1, wn = w & 1;
  int rl = lane & 15, kq = (lane >> 4) * 8, rq = lane >> 4;
  f32x4 accC[4][4] = {};
  f32x4 accS[4][4] = {};
  for (int k0 = 0; k0 < 128; k0 += 32) {
    __syncthreads();
    for (int idx = tid; idx < 1024; idx += 256) {
      int q = idx >> 5, c4 = (idx & 31) * 4;
      ushort4 v = *(const ushort4*)(Yg + ((size_t)bh * 128 + k0 + q) * 256 + c0 + c4);
      Bs[c4 + 0][q] = v.x; Bs[c4 + 1][q] = v.y;
      Bs[c4 + 2][q] = v.z; Bs[c4 + 3][q] = v.w;
    }
    __syncthreads();
    bf16x8 aCh[4], aCl[4], aSh[4], aSl[4], bf[4];
    #pragma unroll
    for (int i = 0; i < 4; i++) {
      int off = (wm * 64 + i * 16 + rl) * 128 + k0 + kq;
      aCh[i] = *(const bf16x8*)(Chi_ + off);
      aCl[i] = *(const bf16x8*)(Clo_ + off);
      aSh[i] = *(const bf16x8*)(Shi_ + off);
      aSl[i] = *(const bf16x8*)(Slo_ + off);
    }
    #pragma unroll
    for (int j = 0; j < 4; j++)
      bf[j] = *(const bf16x8*)&Bs[wn * 64 + j * 16 + rl][kq];
    #pragma unroll
    for (int i = 0; i < 4; i++)
      #pragma unroll
      for (int j = 0; j < 4; j++) {
        accC[i][j] = __builtin_amdgcn_mfma_f32_16x16x32_bf16(aCh[i], bf[j], accC[i][j], 0, 0, 0);
        accC[i][j] = __builtin_amdgcn_mfma_f32_16x16x32_bf16(aCl[i], bf[j], accC[i][j], 0, 0, 0);
        accS[i][j] = __builtin_amdgcn_mfma_f32_16x16x32_bf16(aSh[i], bf[j], accS[i][j], 0, 0, 0);
        accS[i][j] = __builtin_amdgcn_mfma_f32_16x16x32_bf16(aSl[i], bf[j], accS[i][j], 0, 0, 0);
      }
  }
  #pragma unroll
  for (int i = 0; i < 4; i++)
    #pragma unroll
    for (int j = 0; j < 4; j++)
      #pragma unroll
      for (int r = 0; r < 4; r++) {
        int p = wm * 64 + i * 16 + rq * 4 + r;
        if (p < 65) {
          int c = c0 + wn * 64 + j * 16 + rl;
          size_t g = ((size_t)bh * 65 + p) * 256 + c;
          Or[g] = f2b(accC[i][j][r]);
          Oi[g] = f2b(accS[i][j][r]);
        }
      }
}

// ------- MFMA complex DFT over H for fixed (b,kw): O = C*B1 + Ssel*B2 --------
__global__ __launch_bounds__(256) void k_dfth_m(
    const u16* __restrict__ Br_g, const u16* __restrict__ Bi_g,
    const u16* __restrict__ Chi, const u16* __restrict__ Clo,
    const u16* __restrict__ SRhi, const u16* __restrict__ SRlo,
    const u16* __restrict__ SIhi, const u16* __restrict__ SIlo,
    u16* __restrict__ Or, u16* __restrict__ Oi) {
  __shared__ u16 B1s[128][40], B2s[128][40];
  int tid = threadIdx.x;
  int bk = blockIdx.x;
  int b = bk / 65, kw = bk % 65;
  int c0 = (blockIdx.y & 1) * 128;
  int outI = blockIdx.y >> 1;
  const u16* B1g = outI ? Bi_g : Br_g;
  const u16* B2g = outI ? Br_g : Bi_g;
  const u16* Shi = outI ? SIhi : SRhi;
  const u16* Slo = outI ? SIlo : SRlo;
  u16* outp = outI ? Oi : Or;
  int lane = tid & 63, w = tid >> 6;
  int wm = w >> 1, wn = w & 1;
  int rl = lane & 15, kq = (lane >> 4) * 8, rq = lane >> 4;
  f32x4 acc[4][4] = {};
  for (int k0 = 0; k0 < 128; k0 += 32) {
    __syncthreads();
    for (int idx = tid; idx < 1024; idx += 256) {
      int q = idx >> 5, c4 = (idx & 31) * 4;
      size_t g = (((size_t)b * 128 + k0 + q) * 65 + kw) * 256 + c0 + c4;
      ushort4 v1 = *(const ushort4*)(B1g + g);
      ushort4 v2 = *(const ushort4*)(B2g + g);
      B1s[c4 + 0][q] = v1.x; B1s[c4 + 1][q] = v1.y;
      B1s[c4 + 2][q] = v1.z; B1s[c4 + 3][q] = v1.w;
      B2s[c4 + 0][q] = v2.x; B2s[c4 + 1][q] = v2.y;
      B2s[c4 + 2][q] = v2.z; B2s[c4 + 3][q] = v2.w;
    }
    __syncthreads();
    bf16x8 aCh[4], aCl[4], aSh[4], aSl[4], b1[4], b2[4];
    #pragma unroll
    for (int i = 0; i < 4; i++) {
      int off = (wm * 64 + i * 16 + rl) * 128 + k0 + kq;
      aCh[i] = *(const bf16x8*)(Chi + off);
      aCl[i] = *(const bf16x8*)(Clo + off);
      aSh[i] = *(const bf16x8*)(Shi + off);
      aSl[i] = *(const bf16x8*)(Slo + off);
    }
    #pragma unroll
    for (int j = 0; j < 4; j++) {
      b1[j] = *(const bf16x8*)&B1s[wn * 64 + j * 16 + rl][kq];
      b2[j] = *(const bf16x8*)&B2s[wn * 64 + j * 16 + rl][kq];
    }
    #pragma unroll
    for (int i = 0; i < 4; i++)
      #pragma unroll
      for (int j = 0; j < 4; j++) {
        acc[i][j] = __builtin_amdgcn_mfma_f32_16x16x32_bf16(aCh[i], b1[j], acc[i][j], 0, 0, 0);
        acc[i][j] = __builtin_amdgcn_mfma_f32_16x16x32_bf16(aCl[i], b1[j], acc[i][j], 0, 0, 0);
        acc[i][j] = __builtin_amdgcn_mfma_f32_16x16x32_bf16(aSh[i], b2[j], acc[i][j], 0, 0, 0);
        acc[i][j] = __builtin_amdgcn_mfma_f32_16x16x32_bf16(aSl[i], b2[j], acc[i][j], 0, 0, 0);
      }
  }
  #pragma unroll
  for (int i = 0; i < 4; i++)
    #pragma unroll
    for (int j = 0; j < 4; j++)
      #pragma unroll
      for (int r = 0; r < 4; r++) {
        int p = wm * 64 + i * 16 + rq * 4 + r;
        int c = c0 + wn * 64 + j * 16 + rl;
        outp[(((size_t)b * 128 + p) * 65 + kw) * 256 + c] = f2b(acc[i][j][r]);
      }
}

// ------- MFMA inverse rDFT over W + x + ln1out -> X1. K=160 (65r+65i+pad) ----
__global__ __launch_bounds__(256) void k_irfft_m(
    const u16* __restrict__ Ur, const u16* __restrict__ Ui,
    const u16* __restrict__ Whi, const u16* __restrict__ Wlo,
    const float* __restrict__ x_in, const u16* __restrict__ lnout,
    u16* __restrict__ X1) {
  __shared__ u16 Bs[128][40];
  int tid = threadIdx.x;
  int bh = blockIdx.x;
  int c0 = blockIdx.y * 128;
  int lane = tid & 63, w = tid >> 6;
  int wm = w >> 1, wn = w & 1;
  int rl = lane & 15, kq = (lane >> 4) * 8, rq = lane >> 4;
  f32x4 acc[4][4] = {};
  for (int k0 = 0; k0 < 160; k0 += 32) {
    __syncthreads();
    for (int idx = tid; idx < 1024; idx += 256) {
      int q = idx >> 5, c4 = (idx & 31) * 4;
      int grow = k0 + q;
      ushort4 v;
      if (grow < 65)
        v = *(const ushort4*)(Ur + ((size_t)bh * 65 + grow) * 256 + c0 + c4);
      else if (grow < 130)
        v = *(const ushort4*)(Ui + ((size_t)bh * 65 + grow - 65) * 256 + c0 + c4);
      else
        v = make_ushort4(0, 0, 0, 0);
      Bs[c4 + 0][q] = v.x; Bs[c4 + 1][q] = v.y;
      Bs[c4 + 2][q] = v.z; Bs[c4 + 3][q] = v.w;
    }
    __syncthreads();
    bf16x8 ah[4], al[4], bf[4];
    #pragma unroll
    for (int i = 0; i < 4; i++) {
      int off = (wm * 64 + i * 16 + rl) * 160 + k0 + kq;
      ah[i] = *(const bf16x8*)(Whi + off);
      al[i] = *(const bf16x8*)(Wlo + off);
    }
    #pragma unroll
    for (int j = 0; j < 4; j++)
      bf[j] = *(const bf16x8*)&Bs[wn * 64 + j * 16 + rl][kq];
    #pragma unroll
    for (int i = 0; i < 4; i++)
      #pragma unroll
      for (int j = 0; j < 4; j++) {
        acc[i][j] = __builtin_amdgcn_mfma_f32_16x16x32_bf16(ah[i], bf[j], acc[i][j], 0, 0, 0);
        acc[i][j] = __builtin_amdgcn_mfma_f32_16x16x32_bf16(al[i], bf[j], acc[i][j], 0, 0, 0);
      }
  }
  #pragma unroll
  for (int i = 0; i < 4; i++)
    #pragma unroll
    for (int j = 0; j < 4; j++)
      #pragma unroll
      for (int r = 0; r < 4; r++) {
        int p = wm * 64 + i * 16 + rq * 4 + r;
        int c = c0 + wn * 64 + j * 16 + rl;
        size_t g = ((size_t)bh * 128 + p) * 256 + c;
        X1[g] = f2b(x_in[g] + b2f(lnout[g]) + acc[i][j][r]);
      }
}

// ------- fused AFNO MLP, barrier-free (R16 config: 4 n/block, 64 pos/wave) ---
__global__ __launch_bounds__(256) void k_afno_mfma(
    const u16* __restrict__ Zr, const u16* __restrict__ Zi,
    const u16* __restrict__ W1h, const u16* __restrict__ W1l,
    const u16* __restrict__ W2h, const u16* __restrict__ W2l,
    const float* __restrict__ b1, const float* __restrict__ b2,
    u16* __restrict__ Or, u16* __restrict__ Oi) {
  __shared__ u16 o1buf[4][64][74];
  int tid = threadIdx.x;
  int lane = tid & 63, w = tid >> 6;
  int n = blockIdx.x * 4 + w;
  int p0 = blockIdx.y * 64;
  int rl = lane & 15, rq = lane >> 4, kq = rq * 8;
  bf16x8 bfr[4];
  #pragma unroll
  for (int j = 0; j < 4; j++) {
    int p = p0 + j * 16 + rl;
    const u16* src = (kq < 16) ? (Zr + (size_t)p * 256 + n * 16 + kq)
                               : (Zi + (size_t)p * 256 + n * 16 + kq - 16);
    bfr[j] = *(const bf16x8*)src;
  }
  f32x4 acc2[2][4] = {};
  for (int c = 0; c < 4; c++) {
    f32x4 a1[4][4] = {};
    #pragma unroll
    for (int i = 0; i < 4; i++) {
      int out = c * 64 + i * 16 + rl;
      bf16x8 ah = *(const bf16x8*)(W1h + ((size_t)n * 256 + out) * 32 + kq);
      bf16x8 al = *(const bf16x8*)(W1l + ((size_t)n * 256 + out) * 32 + kq);
      #pragma unroll
      for (int j = 0; j < 4; j++) {
        a1[i][j] = __builtin_amdgcn_mfma_f32_16x16x32_bf16(ah, bfr[j], a1[i][j], 0, 0, 0);
        a1[i][j] = __builtin_amdgcn_mfma_f32_16x16x32_bf16(al, bfr[j], a1[i][j], 0, 0, 0);
      }
    }
    #pragma unroll
    for (int i = 0; i < 4; i++) {
      float bv[4];
      #pragma unroll
      for (int r = 0; r < 4; r++) {
        int out = c * 64 + i * 16 + rq * 4 + r;
        bv[r] = (out < 128) ? b1[n * 128 + out] : b1[2048 + n * 128 + out - 128];
      }
      #pragma unroll
      for (int j = 0; j < 4; j++) {
        int pos = j * 16 + rl;
        ushort4 pk;
        u16* pp = &pk.x;
        #pragma unroll
        for (int r = 0; r < 4; r++)
          pp[r] = f2b(fmaxf(a1[i][j][r] + bv[r], 0.0f));
        *(ushort4*)&o1buf[w][pos][(i * 16 + rq * 4) ^ ((pos & 7) << 3)] = pk;
      }
    }
    #pragma unroll
    for (int ks = 0; ks < 2; ks++) {
      int kg = c * 64 + ks * 32 + kq;
      #pragma unroll
      for (int i2 = 0; i2 < 2; i2++) {
        int out2 = i2 * 16 + rl;
        bf16x8 ah = *(const bf16x8*)(W2h + ((size_t)n * 32 + out2) * 256 + kg);
        bf16x8 al = *(const bf16x8*)(W2l + ((size_t)n * 32 + out2) * 256 + kg);
        #pragma unroll
        for (int j = 0; j < 4; j++) {
          int pos = j * 16 + rl;
          bf16x8 bb = *(const bf16x8*)&o1buf[w][pos][(ks * 32 + kq) ^ ((pos & 7) << 3)];
          acc2[i2][j] = __builtin_amdgcn_mfma_f32_16x16x32_bf16(ah, bb, acc2[i2][j], 0, 0, 0);
          acc2[i2][j] = __builtin_amdgcn_mfma_f32_16x16x32_bf16(al, bb, acc2[i2][j], 0, 0, 0);
        }
      }
    }
  }
  #pragma unroll
  for (int i2 = 0; i2 < 2; i2++)
    #pragma unroll
    for (int r = 0; r < 4; r++) {
      int out2 = i2 * 16 + rq * 4 + r;
      float bv = (out2 < 16) ? b2[n * 16 + out2] : b2[256 + n * 16 + out2 - 16];
      int ch = (out2 < 16) ? out2 : out2 - 16;
      #pragma unroll
      for (int j = 0; j < 4; j++) {
        float v = acc2[i2][j][r] + bv;
        v = copysignf(fmaxf(fabsf(v) - LAM, 0.0f), v);
        size_t g = (size_t)(p0 + j * 16 + rl) * 256 + n * 16 + ch;
        if (out2 < 16) Or[g] = f2b(v);
        else Oi[g] = f2b(v);
      }
    }
}

// ------- MFMA GEMM 128x128: C[m,n] = act(A*B^T + bias) (+resid) --------------
template<int ACT, int RT, int OUTF>
__global__ __launch_bounds__(256) void k_mgemm(const u16* __restrict__ Ap,
                                               const u16* __restrict__ Bp,
                                               const float* __restrict__ bias,
                                               const u16* __restrict__ resid,
                                               void* __restrict__ Cp,
                                               int M, int N, int K) {
  __shared__ u16 As[128][40];
  __shared__ u16 Bs[128][40];
  int tid = threadIdx.x;
  int lane = tid & 63, w = tid >> 6;
  int wm = w >> 1, wn = w & 1;
  int m0 = blockIdx.x * 128, n0 = blockIdx.y * 128;
  int srow = tid >> 1, sseg = tid & 1;
  const u16* ag = Ap + (size_t)(m0 + srow) * K + sseg * 16;
  const u16* bg = Bp + (size_t)(n0 + srow) * K + sseg * 16;
  int rl = lane & 15, kq = (lane >> 4) * 8;
  f32x4 acc[4][4] = {};
  for (int k0 = 0; k0 < K; k0 += 32) {
    __syncthreads();
    *(u16x8*)&As[srow][sseg * 16]     = *(const u16x8*)(ag + k0);
    *(u16x8*)&As[srow][sseg * 16 + 8] = *(const u16x8*)(ag + k0 + 8);
    *(u16x8*)&Bs[srow][sseg * 16]     = *(const u16x8*)(bg + k0);
    *(u16x8*)&Bs[srow][sseg * 16 + 8] = *(const u16x8*)(bg + k0 + 8);
    __syncthreads();
    bf16x8 af[4], bf[4];
    #pragma unroll
    for (int i = 0; i < 4; i++) {
      af[i] = *(const bf16x8*)&As[wm * 64 + i * 16 + rl][kq];
      bf[i] = *(const bf16x8*)&Bs[wn * 64 + i * 16 + rl][kq];
    }
    #pragma unroll
    for (int i = 0; i < 4; i++)
      #pragma unroll
      for (int j = 0; j < 4; j++)
        acc[i][j] = __builtin_amdgcn_mfma_f32_16x16x32_bf16(af[i], bf[j], acc[i][j], 0, 0, 0);
  }
  int rq = lane >> 4;
  #pragma unroll
  for (int i = 0; i < 4; i++) {
    #pragma unroll
    for (int j = 0; j < 4; j++) {
      #pragma unroll
      for (int r = 0; r < 4; r++) {
        int m = m0 + wm * 64 + i * 16 + rq * 4 + r;
        int n = n0 + wn * 64 + j * 16 + rl;
        float v = acc[i][j][r] + bias[n];
        if (ACT) v = 0.5f * v * (1.0f + erff(v * 0.70710678118654752f));
        if (RT) v += b2f(resid[(size_t)m * N + n]);
        if (OUTF) ((float*)Cp)[(size_t)m * N + n] = v;
        else ((u16*)Cp)[(size_t)m * N + n] = f2b(v);
      }
    }
  }
}

// ------- fused QKV GEMM + per-head LN on K,V: grid (256, 6) ------------------
__global__ __launch_bounds__(256) void k_mgemm_qkv(
    const u16* __restrict__ Ap,
    const u16* __restrict__ Wk, const u16* __restrict__ Wv, const u16* __restrict__ Wq,
    const float* __restrict__ bk, const float* __restrict__ bv, const float* __restrict__ bq,
    const float* __restrict__ lnkg, const float* __restrict__ lnkb,
    const float* __restrict__ lnvg, const float* __restrict__ lnvb,
    u16* __restrict__ Ko, u16* __restrict__ Vo, u16* __restrict__ Qo) {
  __shared__ u16 As[128][40];
  __shared__ u16 Bs[128][40];
  int sel = blockIdx.y >> 1;
  const u16* Bp = (sel == 0) ? Wk : (sel == 1) ? Wv : Wq;
  const float* bias = (sel == 0) ? bk : (sel == 1) ? bv : bq;
  u16* Cp = (sel == 0) ? Ko : (sel == 1) ? Vo : Qo;
  int tid = threadIdx.x;
  int lane = tid & 63, w = tid >> 6;
  int wm = w >> 1, wn = w & 1;
  int m0 = blockIdx.x * 128, n0 = (blockIdx.y & 1) * 128;
  int srow = tid >> 1, sseg = tid & 1;
  const u16* ag = Ap + (size_t)(m0 + srow) * 256 + sseg * 16;
  const u16* bg = Bp + (size_t)(n0 + srow) * 256 + sseg * 16;
  int rl = lane & 15, kq = (lane >> 4) * 8;
  f32x4 acc[4][4] = {};
  for (int k0 = 0; k0 < 256; k0 += 32) {
    __syncthreads();
    *(u16x8*)&As[srow][sseg * 16]     = *(const u16x8*)(ag + k0);
    *(u16x8*)&As[srow][sseg * 16 + 8] = *(const u16x8*)(ag + k0 + 8);
    *(u16x8*)&Bs[srow][sseg * 16]     = *(const u16x8*)(bg + k0);
    *(u16x8*)&Bs[srow][sseg * 16 + 8] = *(const u16x8*)(bg + k0 + 8);
    __syncthreads();
    bf16x8 af[4], bf[4];
    #pragma unroll
    for (int i = 0; i < 4; i++) {
      af[i] = *(const bf16x8*)&As[wm * 64 + i * 16 + rl][kq];
      bf[i] = *(const bf16x8*)&Bs[wn * 64 + i * 16 + rl][kq];
    }
    #pragma unroll
    for (int i = 0; i < 4; i++)
      #pragma unroll
      for (int j = 0; j < 4; j++)
        acc[i][j] = __builtin_amdgcn_mfma_f32_16x16x32_bf16(af[i], bf[j], acc[i][j], 0, 0, 0);
  }
  int rq = lane >> 4;
  if (sel == 2) {
    #pragma unroll
    for (int i = 0; i < 4; i++)
      #pragma unroll
      for (int j = 0; j < 4; j++)
        #pragma unroll
        for (int r = 0; r < 4; r++) {
          int m = m0 + wm * 64 + i * 16 + rq * 4 + r;
          int n = n0 + wn * 64 + j * 16 + rl;
          Cp[(size_t)m * 256 + n] = f2b(acc[i][j][r] + bias[n]);
        }
  } else {
    const float* g = sel ? lnvg : lnkg;
    const float* bt = sel ? lnvb : lnkb;
    #pragma unroll
    for (int i = 0; i < 4; i++)
      #pragma unroll
      for (int r = 0; r < 4; r++) {
        int m = m0 + wm * 64 + i * 16 + rq * 4 + r;
        #pragma unroll
        for (int hb = 0; hb < 2; hb++) {
          int hbase = n0 + wn * 64 + hb * 32;
          float v0 = acc[i][hb * 2 + 0][r] + bias[hbase + rl];
          float v1 = acc[i][hb * 2 + 1][r] + bias[hbase + 16 + rl];
          float s = v0 + v1;
          s += __shfl_xor(s, 1); s += __shfl_xor(s, 2);
          s += __shfl_xor(s, 4); s += __shfl_xor(s, 8);
          float mu = s * (1.0f / 32.0f);
          float q = (v0 - mu) * (v0 - mu) + (v1 - mu) * (v1 - mu);
          q += __shfl_xor(q, 1); q += __shfl_xor(q, 2);
          q += __shfl_xor(q, 4); q += __shfl_xor(q, 8);
          float rs = rsqrtf(q * (1.0f / 32.0f) + EPSN);
          float o0 = (v0 - mu) * rs * g[hbase + rl] + bt[hbase + rl];
          float o1 = (v1 - mu) * rs * g[hbase + 16 + rl] + bt[hbase + 16 + rl];
          Cp[(size_t)m * 256 + hbase + rl] = f2b(o0);
          Cp[(size_t)m * 256 + hbase + 16 + rl] = f2b(o1);
        }
      }
  }
}

// ------- MFMA GEMM 64x64 tile (FFN down: K=2048, grid (64,4)) ----------------
__global__ __launch_bounds__(256) void k_mgemm_d(const u16* __restrict__ Ap,
                                                 const u16* __restrict__ Bp,
                                                 const float* __restrict__ bias,
                                                 const u16* __restrict__ resid,
                                                 float* __restrict__ Cp,
                                                 int M, int N, int K) {
  __shared__ u16 As[64][40];
  __shared__ u16 Bs[64][40];
  int tid = threadIdx.x;
  int lane = tid & 63, w = tid >> 6;
  int wm = w >> 1, wn = w & 1;
  int m0 = blockIdx.x * 64, n0 = blockIdx.y * 64;
  int srow = tid >> 2, sseg = tid & 3;
  const u16* ag = Ap + (size_t)(m0 + srow) * K + sseg * 8;
  const u16* bg = Bp + (size_t)(n0 + srow) * K + sseg * 8;
  int rl = lane & 15, kq = (lane >> 4) * 8;
  f32x4 acc[2][2] = {};
  for (int k0 = 0; k0 < K; k0 += 32) {
    __syncthreads();
    *(u16x8*)&As[srow][sseg * 8] = *(const u16x8*)(ag + k0);
    *(u16x8*)&Bs[srow][sseg * 8] = *(const u16x8*)(bg + k0);
    __syncthreads();
    bf16x8 af[2], bf[2];
    #pragma unroll
    for (int i = 0; i < 2; i++) {
      af[i] = *(const bf16x8*)&As[wm * 32 + i * 16 + rl][kq];
      bf[i] = *(const bf16x8*)&Bs[wn * 32 + i * 16 + rl][kq];
    }
    #pragma unroll
    for (int i = 0; i < 2; i++)
      #pragma unroll
      for (int j = 0; j < 2; j++)
        acc[i][j] = __builtin_amdgcn_mfma_f32_16x16x32_bf16(af[i], bf[j], acc[i][j], 0, 0, 0);
  }
  int rq = lane >> 4;
  #pragma unroll
  for (int i = 0; i < 2; i++)
    #pragma unroll
    for (int j = 0; j < 2; j++)
      #pragma unroll
      for (int r = 0; r < 4; r++) {
        int m = m0 + wm * 32 + i * 16 + rq * 4 + r;
        int n = n0 + wn * 32 + j * 16 + rl;
        float v = acc[i][j][r] + bias[n] + b2f(resid[(size_t)m * N + n]);
        Cp[(size_t)m * N + n] = v;
      }
}

// ---------------- kv partial sums over 16 chunks of 1024 tokens --------------
__global__ __launch_bounds__(256) void k_kv_partial(const u16* __restrict__ Kb,
                                                    const u16* __restrict__ Vb,
                                                    float* __restrict__ part) {
  __shared__ float kl[64][33], vl[64][33];
  int tid = threadIdx.x;
  int bh = blockIdx.x;
  int b = bh >> 3, h = bh & 7;
  int n0 = blockIdx.y * 1024;
  int d = tid >> 3, eg = tid & 7;
  float acc[4] = {0.f, 0.f, 0.f, 0.f};
  for (int sub = 0; sub < 16; sub++) {
    __syncthreads();
    for (int idx = tid; idx < 64 * 32; idx += 256) {
      int nn = idx >> 5, c = idx & 31;
      size_t o = ((size_t)(b * 16384 + n0 + sub * 64 + nn)) * Cch + h * 32 + c;
      kl[nn][c] = b2f(Kb[o]); vl[nn][c] = b2f(Vb[o]);
    }
    __syncthreads();
    #pragma unroll 4
    for (int nn = 0; nn < 64; nn++) {
      float kd = kl[nn][d];
      #pragma unroll
      for (int j = 0; j < 4; j++) acc[j] += kd * vl[nn][eg * 4 + j];
    }
  }
  size_t base = ((size_t)bh * 16 + blockIdx.y) * 1024 + d * 32 + eg * 4;
  #pragma unroll
  for (int j = 0; j < 4; j++) part[base + j] = acc[j];
}

// reduce partials -> kvT (transposed [e][d]) hi/lo bf16, fp32-accurate pair
__global__ __launch_bounds__(1024) void k_kv_reduce(const float* __restrict__ part,
                                                    u16* __restrict__ kvTh,
                                                    u16* __restrict__ kvTl) {
  int bh = blockIdx.x, o = threadIdx.x;
  float s = 0.f;
  #pragma unroll
  for (int p = 0; p < 16; p++) s += part[((size_t)bh * 16 + p) * 1024 + o];
  s *= (1.0f / 16384.0f);
  int d = o >> 5, e = o & 31;
  u16 hi = f2b(s);
  kvTh[(size_t)bh * 1024 + e * 32 + d] = hi;
  kvTl[(size_t)bh * 1024 + e * 32 + d] = f2b(s - b2f(hi));
}

// ------- MFMA attn: ATT[t, h*32+e] = sum_d Q[t, h*32+d] * kvT[b,h][e][d] ----
__global__ __launch_bounds__(256) void k_attn_m(const u16* __restrict__ Q,
                                                const u16* __restrict__ kvTh,
                                                const u16* __restrict__ kvTl,
                                                u16* __restrict__ ATT) {
  int tid = threadIdx.x;
  int lane = tid & 63, w = tid >> 6;
  int h = blockIdx.y;
  int t0 = blockIdx.x * 64 + w * 16;
  int b = t0 >> 14;
  int rl = lane & 15, rq = lane >> 4, kq = rq * 8;
  bf16x8 a = *(const bf16x8*)(Q + (size_t)(t0 + rl) * 256 + h * 32 + kq);
  const u16* kh = kvTh + (size_t)(b * 8 + h) * 1024;
  const u16* kl = kvTl + (size_t)(b * 8 + h) * 1024;
  f32x4 acc[2] = {};
  #pragma unroll
  for (int j = 0; j < 2; j++) {
    bf16x8 bh_ = *(const bf16x8*)(kh + (j * 16 + rl) * 32 + kq);
    bf16x8 bl_ = *(const bf16x8*)(kl + (j * 16 + rl) * 32 + kq);
    acc[j] = __builtin_amdgcn_mfma_f32_16x16x32_bf16(a, bh_, acc[j], 0, 0, 0);
    acc[j] = __builtin_amdgcn_mfma_f32_16x16x32_bf16(a, bl_, acc[j], 0, 0, 0);
  }
  #pragma unroll
  for (int j = 0; j < 2; j++)
    #pragma unroll
    for (int r = 0; r < 4; r++)
      ATT[(size_t)(t0 + rq * 4 + r) * 256 + h * 32 + j * 16 + rl] = f2b(acc[j][r]);
}

extern "C" void kernel_launch(void* const* d_in, const int* in_sizes, int n_in,
                              void* d_out, int out_size, void* d_ws, size_t ws_size,
                              hipStream_t stream) {
  (void)in_sizes; (void)n_in; (void)out_size; (void)ws_size;
  const float* x    = (const float*)d_in[0];
  const float* w1   = (const float*)d_in[1];
  const float* b1   = (const float*)d_in[2];
  const float* w2   = (const float*)d_in[3];
  const float* b2   = (const float*)d_in[4];
  const float* wq   = (const float*)d_in[5];
  const float* bq   = (const float*)d_in[6];
  const float* wk   = (const float*)d_in[7];
  const float* bk   = (const float*)d_in[8];
  const float* wv   = (const float*)d_in[9];
  const float* bv   = (const float*)d_in[10];
  const float* lnkg = (const float*)d_in[11];
  const float* lnkb = (const float*)d_in[12];
  const float* lnvg = (const float*)d_in[13];
  const float* lnvb = (const float*)d_in[14];
  const float* wo   = (const float*)d_in[15];
  const float* bo   = (const float*)d_in[16];
  const float* wup  = (const float*)d_in[17];
  const float* bup  = (const float*)d_in[18];
  const float* wdn  = (const float*)d_in[19];
  const float* bdn  = (const float*)d_in[20];
  const float* n1g  = (const float*)d_in[21];
  const float* n1b  = (const float*)d_in[22];
  const float* n2g  = (const float*)d_in[23];
  const float* n2b  = (const float*)d_in[24];
  const float* n3g  = (const float*)d_in[25];
  const float* n3b  = (const float*)d_in[26];

  // ws layout (max 51,970,048, proven safe). Qb in d_out scratch.
  char* ws = (char*)d_ws;
  u16* A    = (u16*)(ws + 0);
  u16* S1r  = (u16*)(ws + 16777216);
  u16* S1i  = (u16*)(ws + 25296896);
  u16* S2r  = (u16*)(ws + 33816576);
  u16* S2i  = (u16*)(ws + 42336256);
  u16* X1   = (u16*)(ws + 16777216);
  u16* Vb   = (u16*)(ws + 16777216);
  u16* X2   = (u16*)(ws + 16777216);
  u16* Kb   = (u16*)(ws + 33816576);
  u16* ATT  = (u16*)(ws + 33816576);
  u16* UP   = (u16*)(ws + 33816576);
  u16* wq_b = (u16*)(ws + 33554432);
  u16* wk_b = (u16*)(ws + 33685504);
  u16* wv_b = (u16*)(ws + 50593792);
  u16* wo_b = (u16*)(ws + 50724864);
  u16* wup_b = (u16*)(ws + 16777216);
  u16* wdn_b = (u16*)(ws + 17825792);
  u16* TW   = (u16*)(ws + 50855936);
  float* KVp = (float*)(ws + 50855936);
  u16* kvTh = (u16*)(ws + 51904512);
  u16* kvTl = (u16*)(ws + 51937280);
  float* outp = (float*)d_out;
  u16* Qb  = (u16*)d_out;
  u16* W1h = (u16*)d_out;
  u16* W1l = W1h + 131072;
  u16* W2h = W1h + 262144;
  u16* W2l = W1h + 393216;

  u16 *Cf_h = TW + 0 * 16384, *Cf_l = TW + 1 * 16384;
  u16 *Sf_h = TW + 2 * 16384, *Sf_l = TW + 3 * 16384;
  u16 *Snf_h = TW + 4 * 16384, *Snf_l = TW + 5 * 16384;
  u16 *Cu_h = TW + 6 * 16384, *Cu_l = TW + 7 * 16384;
  u16 *Su_h = TW + 8 * 16384, *Su_l = TW + 9 * 16384;
  u16 *Snu_h = TW + 10 * 16384, *Snu_l = TW + 11 * 16384;
  u16 *Wm_h = TW + 196608, *Wm_l = TW + 217088;

  k_init<<<1152, 256, 0, stream>>>(w1, w2, W1h, W1l, W2h, W2l, TW);

  // ---- AFNO: x1 = x + ln1(x) + irfft2(shrink(mlp(rfft2(ln1(x))))) ----
  k_ln<1><<<8192, 256, 0, stream>>>((const void*)x, n1g, n1b, A);
  k_dftw_m<<<dim3(256, 2), 256, 0, stream>>>(A, Cu_h, Cu_l, Snu_h, Snu_l, S1r, S1i);
  k_dfth_m<<<dim3(130, 4), 256, 0, stream>>>(S1r, S1i, Cf_h, Cf_l, Sf_h, Sf_l, Snf_h, Snf_l, S2r, S2i);
  k_afno_mfma<<<dim3(4, 260), 256, 0, stream>>>(S2r, S2i, W1h, W1l, W2h, W2l, b1, b2, S1r, S1i);
  k_dfth_m<<<dim3(130, 4), 256, 0, stream>>>(S1r, S1i, Cu_h, Cu_l, Snu_h, Snu_l, Su_h, Su_l, S2r, S2i);
  k_irfft_m<<<dim3(256, 2), 256, 0, stream>>>(S2r, S2i, Wm_h, Wm_l, x, A, X1);

  // ---- convert QKV/O weights to bf16 (dead S1i/S2i slack) ----
  k_cvt4<<<256, 256, 0, stream>>>(wq, wk, wv, wo, wq_b, wk_b, wv_b, wo_b, 65536);

  // ---- Galerkin: x2 = ln2(x1) + wo(attn) ; residual = LN2 OUTPUT ----
  k_ln<0><<<8192, 256, 0, stream>>>((const void*)X1, n2g, n2b, A);
  k_mgemm_qkv<<<dim3(256, 6), 256, 0, stream>>>(A, wk_b, wv_b, wq_b, bk, bv, bq,
                                                lnkg, lnkb, lnvg, lnvb, Kb, Vb, Qb);
  k_kv_partial<<<dim3(16, 16), 256, 0, stream>>>(Kb, Vb, KVp);
  k_kv_reduce<<<16, 1024, 0, stream>>>(KVp, kvTh, kvTl);
  k_attn_m<<<dim3(512, 8), 256, 0, stream>>>(Qb, kvTh, kvTl, ATT);
  k_mgemm<0, 1, 0><<<dim3(256, 2), 256, 0, stream>>>(ATT, wo_b, bo, A, (void*)X2, 32768, 256, 256);

  // ---- FFN: out = ln3(x2) + down(gelu(up(ln3))) ; residual = LN3 OUTPUT ----
  k_ln<0><<<8192, 256, 0, stream>>>((const void*)X2, n3g, n3b, A);
  k_cvt2<<<2048, 256, 0, stream>>>(wup, wdn, wup_b, wdn_b, 524288);
  for (int c = 0; c < 8; c++) {
    const u16* Ac = A + (size_t)c * 4096 * 256;
    k_mgemm<1, 0, 0><<<dim3(32, 16), 256, 0, stream>>>(Ac, wup_b, bup, nullptr, (void*)UP, 4096, 2048, 256);
    k_mgemm_d<<<dim3(64, 4), 256, 0, stream>>>(UP, wdn_b, bdn, Ac, outp + (size_t)c * 4096 * 256, 4096, 256, 2048);
  }
}